// Round 5
// baseline (248.843 us; speedup 1.0000x reference)
//
#include <hip/hip_runtime.h>
#include <hip/hip_bf16.h>

// Problem constants
#define BB 8
#define NN 8192
#define CC 64
#define PP 2048
#define KK 16
#define H1 64
#define H2 128
#define K1PAD 160
#define K2PAD 72

typedef float  f32x4 __attribute__((ext_vector_type(4)));
typedef short  s16x8 __attribute__((ext_vector_type(8)));

// ---- workspace layout (bytes) ----
#define OFF_FXT   0u                    // B*N*68 f32 = 17,825,792
#define OFF_PTS4  17825792u             // B*N float4 = 2,097,152
#define OFF_KNN   19922944u             // B*P*16 int  = 1,048,576
#define OFF_W1P   20971520u             // 64*160 bf16 = 20,480
#define OFF_W2P   20992000u             // 128*72 bf16 = 18,432
#define OFF_C1    21010432u             // 64 f32
#define OFF_C2    21010688u             // 128 f32

#define FLTMAX 3.402823466e+38f

static __device__ __forceinline__ unsigned short bf16b(float v) {
    __hip_bfloat16 h = __float2bfloat16(v);
    return *reinterpret_cast<unsigned short*>(&h);
}
static __device__ __forceinline__ unsigned pk2(float a, float b) {
    return ((unsigned)bf16b(b) << 16) | (unsigned)bf16b(a);
}
// wave-local LDS fence: compiler barrier + LDS drain, NO vmcnt drain
#define LDS_FENCE() asm volatile("s_waitcnt lgkmcnt(0)" ::: "memory")

// ---------------- K0: fold BN into weights, write bf16 W1p/W2p + c1/c2 ----
__global__ void k0_weights(const float* __restrict__ W1, const float* __restrict__ b1,
                           const float* __restrict__ g1, const float* __restrict__ be1,
                           const float* __restrict__ m1, const float* __restrict__ v1,
                           const float* __restrict__ W2, const float* __restrict__ b2,
                           const float* __restrict__ g2, const float* __restrict__ be2,
                           const float* __restrict__ m2, const float* __restrict__ v2,
                           unsigned short* __restrict__ w1p, unsigned short* __restrict__ w2p,
                           float* __restrict__ c1, float* __restrict__ c2) {
    int i = blockIdx.x * 256 + threadIdx.x;
    if (i < 64 * K1PAD) {
        int n = i / K1PAD, c = i - n * K1PAD;
        float s = g1[n] * rsqrtf(v1[n] + 1e-5f);
        float val = 0.f;
        if (c < 67)                 val = W1[n * 134 + c] * s;
        else if (c >= 72 && c < 139) val = W1[n * 134 + (c - 5)] * s;
        w1p[i] = bf16b(val);
    }
    int j = i - 64 * K1PAD;
    if (j >= 0 && j < 128 * K2PAD) {
        int o = j / K2PAD, k = j - o * K2PAD;
        float s = g2[o] * rsqrtf(v2[o] + 1e-5f);
        w2p[j] = bf16b((k < 64) ? W2[o * 64 + k] * s : 0.f);
    }
    int l = i - (64 * K1PAD + 128 * K2PAD);
    if (l >= 0 && l < 64) {
        float s = g1[l] * rsqrtf(v1[l] + 1e-5f);
        c1[l] = s * (b1[l] - m1[l]) + be1[l];
    }
    int p = l - 64;
    if (p >= 0 && p < 128) {
        float s = g2[p] * rsqrtf(v2[p] + 1e-5f);
        c2[p] = s * (b2[p] - m2[p]) + be2[p];
    }
}

// ---------------- K1: transpose feat -> fxt[b][n][68], pts4, out0, out2 ----
__global__ __launch_bounds__(512) void k1_prep(const float* __restrict__ xyz,
                                               const float* __restrict__ feat,
                                               float* __restrict__ fxt,
                                               float4* __restrict__ pts4,
                                               float* __restrict__ out0,
                                               float* __restrict__ out2) {
    __shared__ float tile[68][65];
    int b  = blockIdx.x >> 7;
    int n0 = (blockIdx.x & 127) * 64;
    int tx = threadIdx.x & 63, ty = threadIdx.x >> 6;
    for (int c = ty; c < 68; c += 8) {
        float v;
        if (c < 64)       v = feat[((size_t)b * 64 + c) * NN + n0 + tx];
        else if (c < 67)  v = xyz[((size_t)b * NN + n0 + tx) * 3 + (c - 64)];
        else              v = 0.f;
        tile[c][tx] = v;
    }
    __syncthreads();
    size_t base = ((size_t)b * NN + n0) * 68;
    for (int e = threadIdx.x; e < 64 * 68; e += 512) {
        int nl = e / 68, c = e - nl * 68;
        fxt[base + e] = tile[c][nl];
    }
    if (threadIdx.x < 64) {
        int n = n0 + threadIdx.x;
        float x = tile[64][threadIdx.x], y = tile[65][threadIdx.x], z = tile[66][threadIdx.x];
        pts4[(size_t)b * NN + n] = make_float4(x, y, z, x * x + y * y + z * z);
        if (n0 < PP) out2[b * PP + n] = (float)n;
    }
    if (n0 < PP) {
        for (int e = threadIdx.x; e < 64 * 3; e += 512) {
            int nl = e / 3, d = e - nl * 3;
            out0[((size_t)b * PP + n0 + nl) * 3 + d] = tile[64 + d][nl];
        }
    }
}

// ---------------- K2 v4: exact KNN, whole batch staged once, ILP sorts ----
__global__ __launch_bounds__(1024, 4) void k2_knn(const float4* __restrict__ pts4,
                                                  int* __restrict__ knn) {
    __shared__ float4 stage[8192];           // 128 KB
    __shared__ float2 scratch[16][2][64];    // 16 KB dual per-wave buffers
    int lane = threadIdx.x & 63;
    int wv   = threadIdx.x >> 6;
    int b    = blockIdx.x >> 5;
    int q0   = (blockIdx.x & 31) * 64 + wv * 4;
    size_t pb = (size_t)b * NN;

    float4 qc = make_float4(0.f, 0.f, 0.f, 0.f);
    if (lane < 4) qc = pts4[pb + q0 + lane];
    float qx2 = -2.f * qc.x, qy2 = -2.f * qc.y, qz2 = -2.f * qc.z;
    float bx[4], by[4], bz[4];
#pragma unroll
    for (int q = 0; q < 4; ++q) {
        bx[q] = __shfl(qx2, q); by[q] = __shfl(qy2, q); bz[q] = __shfl(qz2, q);
    }

#pragma unroll
    for (int i = 0; i < 8; ++i) {
        int p = i * 1024 + threadIdx.x;
        float4 v = pts4[pb + p];
        int r = p >> 6, c = p & 63;
        stage[(r << 6) | ((c + (r >> 1)) & 63)] = v;
    }
    __syncthreads();   // the only block barrier

    float m[4];
#pragma unroll
    for (int q = 0; q < 4; ++q) m[q] = FLTMAX;
#pragma unroll
    for (int rr = 0; rr < 2; ++rr) {
        int rowbase = (2 * lane + rr) << 6;
#pragma unroll
        for (int j8 = 0; j8 < 8; ++j8) {
            float4 cc[8];
#pragma unroll
            for (int i = 0; i < 8; ++i)
                cc[i] = stage[rowbase | ((j8 * 8 + i + lane) & 63)];
#pragma unroll
            for (int q = 0; q < 4; ++q) {
                float x = bx[q], y = by[q], z = bz[q];
#pragma unroll
                for (int i = 0; i < 8; i += 2) {
                    float e0 = fmaf(z, cc[i].z, fmaf(y, cc[i].y, fmaf(x, cc[i].x, cc[i].w)));
                    float e1 = fmaf(z, cc[i+1].z, fmaf(y, cc[i+1].y, fmaf(x, cc[i+1].x, cc[i+1].w)));
                    m[q] = fminf(fminf(m[q], e0), e1);
                }
            }
        }
    }

    float sv0 = m[0], sv1 = m[1], sv2 = m[2], sv3 = m[3];
#pragma unroll
    for (int k = 2; k <= 64; k <<= 1) {
#pragma unroll
        for (int j = k >> 1; j > 0; j >>= 1) {
            bool keepMin = (((lane & k) == 0) == ((lane & j) == 0));
            float p0 = __shfl_xor(sv0, j, 64);
            float p1 = __shfl_xor(sv1, j, 64);
            float p2 = __shfl_xor(sv2, j, 64);
            float p3 = __shfl_xor(sv3, j, 64);
            sv0 = keepMin ? fminf(sv0, p0) : fmaxf(sv0, p0);
            sv1 = keepMin ? fminf(sv1, p1) : fmaxf(sv1, p1);
            sv2 = keepMin ? fminf(sv2, p2) : fmaxf(sv2, p2);
            sv3 = keepMin ? fminf(sv3, p3) : fmaxf(sv3, p3);
        }
    }
    float T[4];
    T[0] = __shfl(sv0, 15, 64); T[1] = __shfl(sv1, 15, 64);
    T[2] = __shfl(sv2, 15, 64); T[3] = __shfl(sv3, 15, 64);

    unsigned long long below = (lane == 63) ? 0x7FFFFFFFFFFFFFFFull
                                            : ((1ull << lane) - 1ull);
#pragma unroll
    for (int pr = 0; pr < 4; pr += 2) {
        float kd[2]; int kn[2];
#pragma unroll
        for (int u = 0; u < 2; ++u) {
            int q = pr + u;
            float x = bx[q], y = by[q], z = bz[q], tq = T[q];
            unsigned long long rm = __ballot(m[q] <= tq);
            int cnt = 0;
            while (rm) {
                int sl = __ffsll((long long)rm) - 1; rm &= rm - 1;
                int phys = (lane + sl) & 63;
                float4 c0 = stage[((2 * sl) << 6) | phys];
                float4 c1 = stage[((2 * sl + 1) << 6) | phys];
                float e0 = fmaf(z, c0.z, fmaf(y, c0.y, fmaf(x, c0.x, c0.w)));
                float e1 = fmaf(z, c1.z, fmaf(y, c1.y, fmaf(x, c1.x, c1.w)));
                unsigned long long b0 = __ballot(e0 <= tq);
                if (e0 <= tq) {
                    int pos = cnt + __popcll(b0 & below);
                    if (pos < 64)
                        scratch[wv][u][pos] = make_float2(e0, __int_as_float(sl * 128 + lane));
                }
                cnt += __popcll(b0);
                unsigned long long b1 = __ballot(e1 <= tq);
                if (e1 <= tq) {
                    int pos = cnt + __popcll(b1 & below);
                    if (pos < 64)
                        scratch[wv][u][pos] = make_float2(e1, __int_as_float(sl * 128 + 64 + lane));
                }
                cnt += __popcll(b1);
            }
            LDS_FENCE();
            int M = min(cnt, 64);
            float2 kv = scratch[wv][u][lane];
            kd[u] = (lane < M) ? kv.x : FLTMAX;
            kn[u] = (lane < M) ? __float_as_int(kv.y) : 0x7FFFFFFF;
        }
#pragma unroll
        for (int k = 2; k <= 64; k <<= 1) {
#pragma unroll
            for (int j = k >> 1; j > 0; j >>= 1) {
                bool takeMin = (((lane & k) == 0) == ((lane & j) == 0));
                float pd0 = __shfl_xor(kd[0], j, 64); int pn0 = __shfl_xor(kn[0], j, 64);
                float pd1 = __shfl_xor(kd[1], j, 64); int pn1 = __shfl_xor(kn[1], j, 64);
                bool l0 = (pd0 < kd[0]) || (pd0 == kd[0] && pn0 < kn[0]);
                bool s0 = takeMin ? l0 : !l0;
                kd[0] = s0 ? pd0 : kd[0]; kn[0] = s0 ? pn0 : kn[0];
                bool l1 = (pd1 < kd[1]) || (pd1 == kd[1] && pn1 < kn[1]);
                bool s1 = takeMin ? l1 : !l1;
                kd[1] = s1 ? pd1 : kd[1]; kn[1] = s1 ? pn1 : kn[1];
            }
        }
        if (lane < 16) {
            knn[((size_t)(b * PP + q0 + pr)) * KK + lane]     = kn[0];
            knn[((size_t)(b * PP + q0 + pr + 1)) * KK + lane] = kn[1];
        }
        LDS_FENCE();
    }
}

// ---------------- K3 v3: 4-wave blocks, 16 queries, coalesced output ----
// Grid 1024 = 8 batches x 128 q-groups; 4 blocks/CU x 4 waves = 16 waves/CU.
// Wave wv: 4 queries (register-prefetch pipelined), private 7936 B LDS segment:
//   [0,5120) E 16x160 bf16, [5120,7424) h1 16x72 bf16, [7424,7696) t4,
//   [7696,7832) tbd. Pads zero-filled once. Maxpool -> otile[16][132] f32;
//   one __syncthreads; coalesced q-contiguous store (kills 11x write amp).
__global__ __launch_bounds__(256, 4) void k3_mlp(const float* __restrict__ fxt,
                                                 const int* __restrict__ knn,
                                                 const unsigned short* __restrict__ w1p,
                                                 const unsigned short* __restrict__ w2p,
                                                 const float* __restrict__ c1,
                                                 const float* __restrict__ c2,
                                                 float* __restrict__ out1) {
    __shared__ __align__(16) char smem[4 * 7936];
    __shared__ float otile[16][132];
    int lane = threadIdx.x & 63;
    int wv   = threadIdx.x >> 6;
    int b    = blockIdx.x >> 7;
    int qg   = blockIdx.x & 127;
    int qbase = qg * 16;                       // query base within batch
    char* seg = smem + wv * 7936;
    float4* sh_t4 = (float4*)(seg + 7424);
    unsigned* sh_tbd = (unsigned*)(seg + 7696);
    unsigned short* h1l = (unsigned short*)(seg + 5120);
    const float4* fx4 = (const float4*)fxt;

    int col = lane & 15, quad = lane >> 4;
    int r = lane >> 2, s = lane & 3;

    // zero-fill constant pad regions once (E dwords {34,35,70..79} per row;
    // h1 cols 64..71 per row)
#pragma unroll
    for (int i = lane; i < 192; i += 64) {
        int rr = i / 12, jj = i - rr * 12;
        int dw = (jj < 2) ? (34 + jj) : (68 + jj);
        *(unsigned*)(seg + rr * 320 + dw * 4) = 0u;
    }
    {
        int rr = lane >> 2, dd = lane & 3;
        *(unsigned*)(seg + 5120 + rr * 144 + 128 + dd * 4) = 0u;
    }

    s16x8 w1f[5][4];
#pragma unroll
    for (int ks = 0; ks < 5; ++ks)
#pragma unroll
        for (int nt = 0; nt < 4; ++nt)
            w1f[ks][nt] = *(const s16x8*)(w1p + (nt * 16 + col) * K1PAD + ks * 32 + quad * 8);
    s16x8 w2f[2][8];
#pragma unroll
    for (int ks = 0; ks < 2; ++ks)
#pragma unroll
        for (int nt = 0; nt < 8; ++nt)
            w2f[ks][nt] = *(const s16x8*)(w2p + (nt * 16 + col) * K2PAD + ks * 32 + quad * 8);
    float c1v[4], c2v[8];
#pragma unroll
    for (int nt = 0; nt < 4; ++nt) c1v[nt] = c1[nt * 16 + col];
#pragma unroll
    for (int nt = 0; nt < 8; ++nt) c2v[nt] = c2[nt * 16 + col];

    // all 64 knn indices for this wave's 4 queries (contiguous load)
    int idxAll = knn[((size_t)(b * PP + qbase + wv * 4)) * KK + lane];

    float4 cc[2][5];
    float4 tv[2];

#define PREFETCH(buf, qi_) {                                                  \
        int q_ = qbase + wv * 4 + (qi_);                                      \
        tv[buf] = make_float4(0.f, 0.f, 0.f, 0.f);                            \
        if (lane < 17) tv[buf] = fx4[((size_t)b * NN + q_) * 17 + lane];      \
        int nidx_ = __shfl(idxAll, (qi_) * 16 + r, 64);                       \
        const float4* rowp_ = fx4 + ((size_t)b * NN + nidx_) * 17;            \
        cc[buf][0] = rowp_[s];      cc[buf][1] = rowp_[4 + s];                \
        cc[buf][2] = rowp_[8 + s];  cc[buf][3] = rowp_[12 + s];               \
        cc[buf][4] = rowp_[16]; }

    PREFETCH(0, 0);

    for (int qi = 0; qi < 4; ++qi) {
        int cur = qi & 1, nxt = cur ^ 1;
        // stage t row
        if (lane < 17) {
            float4 v = tv[cur];
            sh_t4[lane] = v;
            sh_tbd[lane * 2]     = pk2(v.x, v.y);
            sh_tbd[lane * 2 + 1] = pk2(v.z, v.w);
        }
        LDS_FENCE();
        // build E row r from prefetched registers
        char* erow = seg + r * 320;
#pragma unroll
        for (int j = 0; j < 4; ++j) {
            int c4 = j * 4 + s;
            float4 v = cc[cur][j], t = sh_t4[c4];
            *(unsigned*)(erow + c4 * 8)     = pk2(v.x - t.x, v.y - t.y);
            *(unsigned*)(erow + c4 * 8 + 4) = pk2(v.z - t.z, v.w - t.w);
        }
        if (s == 0) {
            float4 v = cc[cur][4], t = sh_t4[16];
            *(unsigned*)(erow + 128) = pk2(v.x - t.x, v.y - t.y);
            *(unsigned*)(erow + 132) = pk2(v.z - t.z, v.w - t.w);
        }
        for (int j = s; j < 34; j += 4)
            *(unsigned*)(erow + 144 + j * 4) = sh_tbd[j];
        // kick next query's gather while GEMMs run
        if (qi < 3) PREFETCH(nxt, qi + 1);
        LDS_FENCE();
        // GEMM1: h1 = relu(E * W1p^T + c1)
        f32x4 acc1[4];
#pragma unroll
        for (int nt = 0; nt < 4; ++nt) acc1[nt] = (f32x4){0.f, 0.f, 0.f, 0.f};
#pragma unroll
        for (int ks = 0; ks < 5; ++ks) {
            s16x8 a = *(const s16x8*)(seg + col * 320 + ks * 64 + quad * 16);
#pragma unroll
            for (int nt = 0; nt < 4; ++nt)
                acc1[nt] = __builtin_amdgcn_mfma_f32_16x16x32_bf16(a, w1f[ks][nt], acc1[nt], 0, 0, 0);
        }
#pragma unroll
        for (int nt = 0; nt < 4; ++nt) {
#pragma unroll
            for (int rr = 0; rr < 4; ++rr) {
                float y = fmaxf(acc1[nt][rr] + c1v[nt], 0.f);
                h1l[(quad * 4 + rr) * K2PAD + nt * 16 + col] = bf16b(y);
            }
        }
        LDS_FENCE();
        // GEMM2 + maxpool over 16 edges
        f32x4 acc2[8];
#pragma unroll
        for (int nt = 0; nt < 8; ++nt) acc2[nt] = (f32x4){0.f, 0.f, 0.f, 0.f};
#pragma unroll
        for (int ks = 0; ks < 2; ++ks) {
            s16x8 a = *(const s16x8*)(seg + 5120 + col * 144 + ks * 64 + quad * 16);
#pragma unroll
            for (int nt = 0; nt < 8; ++nt)
                acc2[nt] = __builtin_amdgcn_mfma_f32_16x16x32_bf16(a, w2f[ks][nt], acc2[nt], 0, 0, 0);
        }
#pragma unroll
        for (int nt = 0; nt < 8; ++nt) {
            float m0 = fmaxf(fmaxf(acc2[nt][0], acc2[nt][1]), fmaxf(acc2[nt][2], acc2[nt][3]));
            m0 = m0 + c2v[nt];
            m0 = fmaxf(m0, 0.f);
            m0 = fmaxf(m0, __shfl_xor(m0, 16, 64));
            m0 = fmaxf(m0, __shfl_xor(m0, 32, 64));
            if (quad == 0)
                otile[wv * 4 + qi][nt * 16 + col] = m0;
        }
        LDS_FENCE();
    }
    __syncthreads();
    // coalesced store: consecutive threads -> consecutive q, same channel
    for (int i = threadIdx.x; i < H2 * 16; i += 256) {
        int ch = i >> 4, q = i & 15;
        out1[((size_t)(b * H2 + ch)) * PP + qbase + q] = otile[q][ch];
    }
#undef PREFETCH
}

extern "C" void kernel_launch(void* const* d_in, const int* in_sizes, int n_in,
                              void* d_out, int out_size, void* d_ws, size_t ws_size,
                              hipStream_t stream) {
    const float* xyz  = (const float*)d_in[0];
    const float* feat = (const float*)d_in[1];
    const float* W1   = (const float*)d_in[2];
    const float* b1   = (const float*)d_in[3];
    const float* g1   = (const float*)d_in[4];
    const float* be1  = (const float*)d_in[5];
    const float* m1   = (const float*)d_in[6];
    const float* v1   = (const float*)d_in[7];
    const float* W2   = (const float*)d_in[8];
    const float* b2   = (const float*)d_in[9];
    const float* g2   = (const float*)d_in[10];
    const float* be2  = (const float*)d_in[11];
    const float* m2   = (const float*)d_in[12];
    const float* v2   = (const float*)d_in[13];

    char* ws = (char*)d_ws;
    float*          fxt  = (float*)(ws + OFF_FXT);
    float4*         pts4 = (float4*)(ws + OFF_PTS4);
    int*            knn  = (int*)(ws + OFF_KNN);
    unsigned short* w1p  = (unsigned short*)(ws + OFF_W1P);
    unsigned short* w2p  = (unsigned short*)(ws + OFF_W2P);
    float*          c1   = (float*)(ws + OFF_C1);
    float*          c2   = (float*)(ws + OFF_C2);

    float* out0 = (float*)d_out;
    float* out1 = out0 + (size_t)BB * PP * 3;
    float* out2 = out1 + (size_t)BB * H2 * PP;

    hipLaunchKernelGGL(k0_weights, dim3(77), dim3(256), 0, stream,
                       W1, b1, g1, be1, m1, v1, W2, b2, g2, be2, m2, v2,
                       w1p, w2p, c1, c2);
    hipLaunchKernelGGL(k1_prep, dim3(1024), dim3(512), 0, stream,
                       xyz, feat, fxt, pts4, out0, out2);
    hipLaunchKernelGGL(k2_knn, dim3(256), dim3(1024), 0, stream, pts4, knn);
    hipLaunchKernelGGL(k3_mlp, dim3(1024), dim3(256), 0, stream,
                       fxt, knn, w1p, w2p, c1, c2, out1);
}

// Round 6
// 172.835 us; speedup vs baseline: 1.4398x; 1.4398x over previous
//
#include <hip/hip_runtime.h>
#include <hip/hip_bf16.h>

// Problem constants
#define BB 8
#define NN 8192
#define CC 64
#define PP 2048
#define KK 16
#define H1 64
#define H2 128
#define K1PAD 160
#define K2PAD 72

typedef float  f32x4 __attribute__((ext_vector_type(4)));
typedef short  s16x8 __attribute__((ext_vector_type(8)));

// ---- workspace layout (bytes) ----
#define OFF_FXT   0u                    // B*N*68 f32 = 17,825,792
#define OFF_PTS4  17825792u             // B*N float4 = 2,097,152
#define OFF_KNN   19922944u             // B*P*16 int  = 1,048,576
#define OFF_W1P   20971520u             // 64*160 bf16 = 20,480
#define OFF_W2P   20992000u             // 128*72 bf16 = 18,432
#define OFF_C1    21010432u             // 64 f32
#define OFF_C2    21010688u             // 128 f32

#define FLTMAX 3.402823466e+38f

static __device__ __forceinline__ unsigned short bf16b(float v) {
    __hip_bfloat16 h = __float2bfloat16(v);
    return *reinterpret_cast<unsigned short*>(&h);
}
static __device__ __forceinline__ unsigned pk2(float a, float b) {
    return ((unsigned)bf16b(b) << 16) | (unsigned)bf16b(a);
}
// wave-local LDS fence: compiler barrier + LDS drain, NO vmcnt drain
#define LDS_FENCE() asm volatile("s_waitcnt lgkmcnt(0)" ::: "memory")

// ---------------- K0: fold BN into weights, write bf16 W1p/W2p + c1/c2 ----
__global__ void k0_weights(const float* __restrict__ W1, const float* __restrict__ b1,
                           const float* __restrict__ g1, const float* __restrict__ be1,
                           const float* __restrict__ m1, const float* __restrict__ v1,
                           const float* __restrict__ W2, const float* __restrict__ b2,
                           const float* __restrict__ g2, const float* __restrict__ be2,
                           const float* __restrict__ m2, const float* __restrict__ v2,
                           unsigned short* __restrict__ w1p, unsigned short* __restrict__ w2p,
                           float* __restrict__ c1, float* __restrict__ c2) {
    int i = blockIdx.x * 256 + threadIdx.x;
    if (i < 64 * K1PAD) {
        int n = i / K1PAD, c = i - n * K1PAD;
        float s = g1[n] * rsqrtf(v1[n] + 1e-5f);
        float val = 0.f;
        if (c < 67)                 val = W1[n * 134 + c] * s;
        else if (c >= 72 && c < 139) val = W1[n * 134 + (c - 5)] * s;
        w1p[i] = bf16b(val);
    }
    int j = i - 64 * K1PAD;
    if (j >= 0 && j < 128 * K2PAD) {
        int o = j / K2PAD, k = j - o * K2PAD;
        float s = g2[o] * rsqrtf(v2[o] + 1e-5f);
        w2p[j] = bf16b((k < 64) ? W2[o * 64 + k] * s : 0.f);
    }
    int l = i - (64 * K1PAD + 128 * K2PAD);
    if (l >= 0 && l < 64) {
        float s = g1[l] * rsqrtf(v1[l] + 1e-5f);
        c1[l] = s * (b1[l] - m1[l]) + be1[l];
    }
    int p = l - 64;
    if (p >= 0 && p < 128) {
        float s = g2[p] * rsqrtf(v2[p] + 1e-5f);
        c2[p] = s * (b2[p] - m2[p]) + be2[p];
    }
}

// ---------------- K1: transpose feat -> fxt[b][n][68], pts4, out0, out2 ----
__global__ __launch_bounds__(512) void k1_prep(const float* __restrict__ xyz,
                                               const float* __restrict__ feat,
                                               float* __restrict__ fxt,
                                               float4* __restrict__ pts4,
                                               float* __restrict__ out0,
                                               float* __restrict__ out2) {
    __shared__ float tile[68][65];
    int b  = blockIdx.x >> 7;
    int n0 = (blockIdx.x & 127) * 64;
    int tx = threadIdx.x & 63, ty = threadIdx.x >> 6;
    for (int c = ty; c < 68; c += 8) {
        float v;
        if (c < 64)       v = feat[((size_t)b * 64 + c) * NN + n0 + tx];
        else if (c < 67)  v = xyz[((size_t)b * NN + n0 + tx) * 3 + (c - 64)];
        else              v = 0.f;
        tile[c][tx] = v;
    }
    __syncthreads();
    size_t base = ((size_t)b * NN + n0) * 68;
    for (int e = threadIdx.x; e < 64 * 68; e += 512) {
        int nl = e / 68, c = e - nl * 68;
        fxt[base + e] = tile[c][nl];
    }
    if (threadIdx.x < 64) {
        int n = n0 + threadIdx.x;
        float x = tile[64][threadIdx.x], y = tile[65][threadIdx.x], z = tile[66][threadIdx.x];
        pts4[(size_t)b * NN + n] = make_float4(x, y, z, x * x + y * y + z * z);
        if (n0 < PP) out2[b * PP + n] = (float)n;
    }
    if (n0 < PP) {
        for (int e = threadIdx.x; e < 64 * 3; e += 512) {
            int nl = e / 3, d = e - nl * 3;
            out0[((size_t)b * PP + n0 + nl) * 3 + d] = tile[64 + d][nl];
        }
    }
}

// ---------------- K2 v4: exact KNN, whole batch staged once, ILP sorts ----
__global__ __launch_bounds__(1024, 4) void k2_knn(const float4* __restrict__ pts4,
                                                  int* __restrict__ knn) {
    __shared__ float4 stage[8192];           // 128 KB
    __shared__ float2 scratch[16][2][64];    // 16 KB dual per-wave buffers
    int lane = threadIdx.x & 63;
    int wv   = threadIdx.x >> 6;
    int b    = blockIdx.x >> 5;
    int q0   = (blockIdx.x & 31) * 64 + wv * 4;
    size_t pb = (size_t)b * NN;

    float4 qc = make_float4(0.f, 0.f, 0.f, 0.f);
    if (lane < 4) qc = pts4[pb + q0 + lane];
    float qx2 = -2.f * qc.x, qy2 = -2.f * qc.y, qz2 = -2.f * qc.z;
    float bx[4], by[4], bz[4];
#pragma unroll
    for (int q = 0; q < 4; ++q) {
        bx[q] = __shfl(qx2, q); by[q] = __shfl(qy2, q); bz[q] = __shfl(qz2, q);
    }

#pragma unroll
    for (int i = 0; i < 8; ++i) {
        int p = i * 1024 + threadIdx.x;
        float4 v = pts4[pb + p];
        int r = p >> 6, c = p & 63;
        stage[(r << 6) | ((c + (r >> 1)) & 63)] = v;
    }
    __syncthreads();   // the only block barrier

    float m[4];
#pragma unroll
    for (int q = 0; q < 4; ++q) m[q] = FLTMAX;
#pragma unroll
    for (int rr = 0; rr < 2; ++rr) {
        int rowbase = (2 * lane + rr) << 6;
#pragma unroll
        for (int j8 = 0; j8 < 8; ++j8) {
            float4 cc[8];
#pragma unroll
            for (int i = 0; i < 8; ++i)
                cc[i] = stage[rowbase | ((j8 * 8 + i + lane) & 63)];
#pragma unroll
            for (int q = 0; q < 4; ++q) {
                float x = bx[q], y = by[q], z = bz[q];
#pragma unroll
                for (int i = 0; i < 8; i += 2) {
                    float e0 = fmaf(z, cc[i].z, fmaf(y, cc[i].y, fmaf(x, cc[i].x, cc[i].w)));
                    float e1 = fmaf(z, cc[i+1].z, fmaf(y, cc[i+1].y, fmaf(x, cc[i+1].x, cc[i+1].w)));
                    m[q] = fminf(fminf(m[q], e0), e1);
                }
            }
        }
    }

    float sv0 = m[0], sv1 = m[1], sv2 = m[2], sv3 = m[3];
#pragma unroll
    for (int k = 2; k <= 64; k <<= 1) {
#pragma unroll
        for (int j = k >> 1; j > 0; j >>= 1) {
            bool keepMin = (((lane & k) == 0) == ((lane & j) == 0));
            float p0 = __shfl_xor(sv0, j, 64);
            float p1 = __shfl_xor(sv1, j, 64);
            float p2 = __shfl_xor(sv2, j, 64);
            float p3 = __shfl_xor(sv3, j, 64);
            sv0 = keepMin ? fminf(sv0, p0) : fmaxf(sv0, p0);
            sv1 = keepMin ? fminf(sv1, p1) : fmaxf(sv1, p1);
            sv2 = keepMin ? fminf(sv2, p2) : fmaxf(sv2, p2);
            sv3 = keepMin ? fminf(sv3, p3) : fmaxf(sv3, p3);
        }
    }
    float T[4];
    T[0] = __shfl(sv0, 15, 64); T[1] = __shfl(sv1, 15, 64);
    T[2] = __shfl(sv2, 15, 64); T[3] = __shfl(sv3, 15, 64);

    unsigned long long below = (lane == 63) ? 0x7FFFFFFFFFFFFFFFull
                                            : ((1ull << lane) - 1ull);
#pragma unroll
    for (int pr = 0; pr < 4; pr += 2) {
        float kd[2]; int kn[2];
#pragma unroll
        for (int u = 0; u < 2; ++u) {
            int q = pr + u;
            float x = bx[q], y = by[q], z = bz[q], tq = T[q];
            unsigned long long rm = __ballot(m[q] <= tq);
            int cnt = 0;
            while (rm) {
                int sl = __ffsll((long long)rm) - 1; rm &= rm - 1;
                int phys = (lane + sl) & 63;
                float4 c0 = stage[((2 * sl) << 6) | phys];
                float4 c1 = stage[((2 * sl + 1) << 6) | phys];
                float e0 = fmaf(z, c0.z, fmaf(y, c0.y, fmaf(x, c0.x, c0.w)));
                float e1 = fmaf(z, c1.z, fmaf(y, c1.y, fmaf(x, c1.x, c1.w)));
                unsigned long long b0 = __ballot(e0 <= tq);
                if (e0 <= tq) {
                    int pos = cnt + __popcll(b0 & below);
                    if (pos < 64)
                        scratch[wv][u][pos] = make_float2(e0, __int_as_float(sl * 128 + lane));
                }
                cnt += __popcll(b0);
                unsigned long long b1 = __ballot(e1 <= tq);
                if (e1 <= tq) {
                    int pos = cnt + __popcll(b1 & below);
                    if (pos < 64)
                        scratch[wv][u][pos] = make_float2(e1, __int_as_float(sl * 128 + 64 + lane));
                }
                cnt += __popcll(b1);
            }
            LDS_FENCE();
            int M = min(cnt, 64);
            float2 kv = scratch[wv][u][lane];
            kd[u] = (lane < M) ? kv.x : FLTMAX;
            kn[u] = (lane < M) ? __float_as_int(kv.y) : 0x7FFFFFFF;
        }
#pragma unroll
        for (int k = 2; k <= 64; k <<= 1) {
#pragma unroll
            for (int j = k >> 1; j > 0; j >>= 1) {
                bool takeMin = (((lane & k) == 0) == ((lane & j) == 0));
                float pd0 = __shfl_xor(kd[0], j, 64); int pn0 = __shfl_xor(kn[0], j, 64);
                float pd1 = __shfl_xor(kd[1], j, 64); int pn1 = __shfl_xor(kn[1], j, 64);
                bool l0 = (pd0 < kd[0]) || (pd0 == kd[0] && pn0 < kn[0]);
                bool s0 = takeMin ? l0 : !l0;
                kd[0] = s0 ? pd0 : kd[0]; kn[0] = s0 ? pn0 : kn[0];
                bool l1 = (pd1 < kd[1]) || (pd1 == kd[1] && pn1 < kn[1]);
                bool s1 = takeMin ? l1 : !l1;
                kd[1] = s1 ? pd1 : kd[1]; kn[1] = s1 ? pn1 : kn[1];
            }
        }
        if (lane < 16) {
            knn[((size_t)(b * PP + q0 + pr)) * KK + lane]     = kn[0];
            knn[((size_t)(b * PP + q0 + pr + 1)) * KK + lane] = kn[1];
        }
        LDS_FENCE();
    }
}

// ---------------- K3 v4: no-spill 4-wave blocks, w1 in LDS, h1 overlay ----
// Grid 1024; b = blk&7 (XCD-affine: one batch per XCD's L2), qg = blk>>3.
// launch_bounds(256,2): 256-VGPR budget, w2f(64)+cc(40)+acc stays resident.
// w1 fragments in LDS (stride 168 bf16 -> 2 lanes/bank, free). Per-wave seg
// 5632 B: E 16x160 bf16 at [0,5120) with h1 16x72 bf16 OVERLAID at [0,2304)
// (phases strictly ordered by in-wave LDS ordering + lgkm fences; E/h1 K-pads
// re-zeroed each phase since regions alias). Maxpool -> otile, coalesced store.
__global__ __launch_bounds__(256, 2) void k3_mlp(const float* __restrict__ fxt,
                                                 const int* __restrict__ knn,
                                                 const unsigned short* __restrict__ w1p,
                                                 const unsigned short* __restrict__ w2p,
                                                 const float* __restrict__ c1,
                                                 const float* __restrict__ c2,
                                                 float* __restrict__ out1) {
    __shared__ __align__(16) char smem[4 * 5632];
    __shared__ float otile[16][132];
    __shared__ __align__(16) unsigned short w1lds[64 * 168];   // 21,504 B
    int lane = threadIdx.x & 63;
    int wv   = threadIdx.x >> 6;
    int b    = blockIdx.x & 7;        // XCD-aware batch assignment
    int qg   = blockIdx.x >> 3;
    int qbase = qg * 16;
    char* seg = smem + wv * 5632;
    float4* sh_t4 = (float4*)(seg + 5120);
    unsigned* sh_tbd = (unsigned*)(seg + 5392);
    unsigned short* h1l = (unsigned short*)(seg);              // overlaid on E
    const float4* fx4 = (const float4*)fxt;

    int col = lane & 15, quad = lane >> 4;
    int r = lane >> 2, s = lane & 3;

    // stage w1p (64x160) into LDS rows of stride 168 (bank-balanced fragments)
    {
        const unsigned* src = (const unsigned*)w1p;
        unsigned* dst = (unsigned*)w1lds;
        for (int t = threadIdx.x; t < 5120; t += 256) {
            int row = t / 80, c = t - row * 80;
            dst[row * 84 + c] = src[t];
        }
    }

    s16x8 w2f[2][8];
#pragma unroll
    for (int ks = 0; ks < 2; ++ks)
#pragma unroll
        for (int nt = 0; nt < 8; ++nt)
            w2f[ks][nt] = *(const s16x8*)(w2p + (nt * 16 + col) * K2PAD + ks * 32 + quad * 8);
    float c1v[4], c2v[8];
#pragma unroll
    for (int nt = 0; nt < 4; ++nt) c1v[nt] = c1[nt * 16 + col];
#pragma unroll
    for (int nt = 0; nt < 8; ++nt) c2v[nt] = c2[nt * 16 + col];

    // all 64 knn indices for this wave's 4 queries (contiguous load)
    int idxAll = knn[((size_t)(b * PP + qbase + wv * 4)) * KK + lane];

    __syncthreads();   // w1lds visible to all waves

    float4 cc[2][5];
    float4 tv[2];

#define PREFETCH(buf, qi_) {                                                  \
        int q_ = qbase + wv * 4 + (qi_);                                      \
        tv[buf] = make_float4(0.f, 0.f, 0.f, 0.f);                            \
        if (lane < 17) tv[buf] = fx4[((size_t)b * NN + q_) * 17 + lane];      \
        int nidx_ = __shfl(idxAll, (qi_) * 16 + r, 64);                       \
        const float4* rowp_ = fx4 + ((size_t)b * NN + nidx_) * 17;            \
        cc[buf][0] = rowp_[s];      cc[buf][1] = rowp_[4 + s];                \
        cc[buf][2] = rowp_[8 + s];  cc[buf][3] = rowp_[12 + s];               \
        cc[buf][4] = rowp_[16]; }

    PREFETCH(0, 0);

#pragma unroll
    for (int qi = 0; qi < 4; ++qi) {
        int cur = qi & 1, nxt = cur ^ 1;
        // stage t row
        if (lane < 17) {
            float4 v = tv[cur];
            sh_t4[lane] = v;
            sh_tbd[lane * 2]     = pk2(v.x, v.y);
            sh_tbd[lane * 2 + 1] = pk2(v.z, v.w);
        }
        LDS_FENCE();
        // build E row r from prefetched registers + re-zero E K-pads
        char* erow = seg + r * 320;
#pragma unroll
        for (int j = 0; j < 4; ++j) {
            int c4 = j * 4 + s;
            float4 v = cc[cur][j], t = sh_t4[c4];
            *(unsigned*)(erow + c4 * 8)     = pk2(v.x - t.x, v.y - t.y);
            *(unsigned*)(erow + c4 * 8 + 4) = pk2(v.z - t.z, v.w - t.w);
        }
        if (s == 0) {
            float4 v = cc[cur][4], t = sh_t4[16];
            *(unsigned*)(erow + 128) = pk2(v.x - t.x, v.y - t.y);
            *(unsigned*)(erow + 132) = pk2(v.z - t.z, v.w - t.w);
        }
        for (int j = s; j < 34; j += 4)
            *(unsigned*)(erow + 144 + j * 4) = sh_tbd[j];
#pragma unroll
        for (int i = lane; i < 192; i += 64) {            // E pad dwords
            int rr = i / 12, jj = i - rr * 12;
            int dw = (jj < 2) ? (34 + jj) : (68 + jj);
            *(unsigned*)(seg + rr * 320 + dw * 4) = 0u;
        }
        // kick next query's gather while GEMMs run
        if (qi < 3) PREFETCH(nxt, qi + 1);
        LDS_FENCE();
        // GEMM1: h1 = relu(E * W1^T + c1); B-fragments from w1lds
        f32x4 acc1[4];
#pragma unroll
        for (int nt = 0; nt < 4; ++nt) acc1[nt] = (f32x4){0.f, 0.f, 0.f, 0.f};
#pragma unroll
        for (int ks = 0; ks < 5; ++ks) {
            s16x8 a = *(const s16x8*)(seg + col * 320 + ks * 64 + quad * 16);
#pragma unroll
            for (int nt = 0; nt < 4; ++nt) {
                s16x8 bf = *(const s16x8*)(w1lds + (nt * 16 + col) * 168 + ks * 32 + quad * 8);
                acc1[nt] = __builtin_amdgcn_mfma_f32_16x16x32_bf16(a, bf, acc1[nt], 0, 0, 0);
            }
        }
        // write h1 (overlaid on E; E fully consumed by in-order LDS reads)
#pragma unroll
        for (int nt = 0; nt < 4; ++nt) {
#pragma unroll
            for (int rr = 0; rr < 4; ++rr) {
                float y = fmaxf(acc1[nt][rr] + c1v[nt], 0.f);
                h1l[(quad * 4 + rr) * K2PAD + nt * 16 + col] = bf16b(y);
            }
        }
        {   // re-zero h1 K-pad (cols 64..71): 16 rows x 4 dwords, 1/lane
            int rr = lane >> 2, dd = lane & 3;
            *(unsigned*)(seg + rr * 144 + 128 + dd * 4) = 0u;
        }
        LDS_FENCE();
        // GEMM2 + maxpool over 16 edges
        f32x4 acc2[8];
#pragma unroll
        for (int nt = 0; nt < 8; ++nt) acc2[nt] = (f32x4){0.f, 0.f, 0.f, 0.f};
#pragma unroll
        for (int ks = 0; ks < 2; ++ks) {
            s16x8 a = *(const s16x8*)(seg + col * 144 + ks * 64 + quad * 16);
#pragma unroll
            for (int nt = 0; nt < 8; ++nt)
                acc2[nt] = __builtin_amdgcn_mfma_f32_16x16x32_bf16(a, w2f[ks][nt], acc2[nt], 0, 0, 0);
        }
#pragma unroll
        for (int nt = 0; nt < 8; ++nt) {
            float m0 = fmaxf(fmaxf(acc2[nt][0], acc2[nt][1]), fmaxf(acc2[nt][2], acc2[nt][3]));
            m0 = m0 + c2v[nt];
            m0 = fmaxf(m0, 0.f);
            m0 = fmaxf(m0, __shfl_xor(m0, 16, 64));
            m0 = fmaxf(m0, __shfl_xor(m0, 32, 64));
            if (quad == 0)
                otile[wv * 4 + qi][nt * 16 + col] = m0;
        }
        LDS_FENCE();
    }
    __syncthreads();
    // coalesced store: consecutive threads -> consecutive q, same channel
    for (int i = threadIdx.x; i < H2 * 16; i += 256) {
        int ch = i >> 4, q = i & 15;
        out1[((size_t)(b * H2 + ch)) * PP + qbase + q] = otile[q][ch];
    }
#undef PREFETCH
}

extern "C" void kernel_launch(void* const* d_in, const int* in_sizes, int n_in,
                              void* d_out, int out_size, void* d_ws, size_t ws_size,
                              hipStream_t stream) {
    const float* xyz  = (const float*)d_in[0];
    const float* feat = (const float*)d_in[1];
    const float* W1   = (const float*)d_in[2];
    const float* b1   = (const float*)d_in[3];
    const float* g1   = (const float*)d_in[4];
    const float* be1  = (const float*)d_in[5];
    const float* m1   = (const float*)d_in[6];
    const float* v1   = (const float*)d_in[7];
    const float* W2   = (const float*)d_in[8];
    const float* b2   = (const float*)d_in[9];
    const float* g2   = (const float*)d_in[10];
    const float* be2  = (const float*)d_in[11];
    const float* m2   = (const float*)d_in[12];
    const float* v2   = (const float*)d_in[13];

    char* ws = (char*)d_ws;
    float*          fxt  = (float*)(ws + OFF_FXT);
    float4*         pts4 = (float4*)(ws + OFF_PTS4);
    int*            knn  = (int*)(ws + OFF_KNN);
    unsigned short* w1p  = (unsigned short*)(ws + OFF_W1P);
    unsigned short* w2p  = (unsigned short*)(ws + OFF_W2P);
    float*          c1   = (float*)(ws + OFF_C1);
    float*          c2   = (float*)(ws + OFF_C2);

    float* out0 = (float*)d_out;
    float* out1 = out0 + (size_t)BB * PP * 3;
    float* out2 = out1 + (size_t)BB * H2 * PP;

    hipLaunchKernelGGL(k0_weights, dim3(77), dim3(256), 0, stream,
                       W1, b1, g1, be1, m1, v1, W2, b2, g2, be2, m2, v2,
                       w1p, w2p, c1, c2);
    hipLaunchKernelGGL(k1_prep, dim3(1024), dim3(512), 0, stream,
                       xyz, feat, fxt, pts4, out0, out2);
    hipLaunchKernelGGL(k2_knn, dim3(256), dim3(1024), 0, stream, pts4, knn);
    hipLaunchKernelGGL(k3_mlp, dim3(1024), dim3(256), 0, stream,
                       fxt, knn, w1p, w2p, c1, c2, out1);
}

// Round 7
// 168.986 us; speedup vs baseline: 1.4726x; 1.0228x over previous
//
#include <hip/hip_runtime.h>
#include <hip/hip_bf16.h>

// Problem constants
#define BB 8
#define NN 8192
#define CC 64
#define PP 2048
#define KK 16
#define H1 64
#define H2 128
#define K1PAD 160
#define K2PAD 72

typedef float  f32x4 __attribute__((ext_vector_type(4)));
typedef short  s16x8 __attribute__((ext_vector_type(8)));

// ---- workspace layout (bytes) ----
#define OFF_FXT   0u                    // B*N*68 f32 = 17,825,792
#define OFF_PTS4  17825792u             // B*N float4 = 2,097,152
#define OFF_KNN   19922944u             // B*P*16 int  = 1,048,576
#define OFF_W1P   20971520u             // 64*160 bf16 = 20,480
#define OFF_W2P   20992000u             // 128*72 bf16 = 18,432
#define OFF_C1    21010432u             // 64 f32
#define OFF_C2    21010688u             // 128 f32

#define FLTMAX 3.402823466e+38f

static __device__ __forceinline__ unsigned short bf16b(float v) {
    __hip_bfloat16 h = __float2bfloat16(v);
    return *reinterpret_cast<unsigned short*>(&h);
}
static __device__ __forceinline__ unsigned pk2(float a, float b) {
    return ((unsigned)bf16b(b) << 16) | (unsigned)bf16b(a);
}
// wave-local LDS fence: compiler barrier + LDS drain, NO vmcnt drain
#define LDS_FENCE() asm volatile("s_waitcnt lgkmcnt(0)" ::: "memory")

// ---------------- K0: fold BN into weights, write bf16 W1p/W2p + c1/c2 ----
__global__ void k0_weights(const float* __restrict__ W1, const float* __restrict__ b1,
                           const float* __restrict__ g1, const float* __restrict__ be1,
                           const float* __restrict__ m1, const float* __restrict__ v1,
                           const float* __restrict__ W2, const float* __restrict__ b2,
                           const float* __restrict__ g2, const float* __restrict__ be2,
                           const float* __restrict__ m2, const float* __restrict__ v2,
                           unsigned short* __restrict__ w1p, unsigned short* __restrict__ w2p,
                           float* __restrict__ c1, float* __restrict__ c2) {
    int i = blockIdx.x * 256 + threadIdx.x;
    if (i < 64 * K1PAD) {
        int n = i / K1PAD, c = i - n * K1PAD;
        float s = g1[n] * rsqrtf(v1[n] + 1e-5f);
        float val = 0.f;
        if (c < 67)                 val = W1[n * 134 + c] * s;
        else if (c >= 72 && c < 139) val = W1[n * 134 + (c - 5)] * s;
        w1p[i] = bf16b(val);
    }
    int j = i - 64 * K1PAD;
    if (j >= 0 && j < 128 * K2PAD) {
        int o = j / K2PAD, k = j - o * K2PAD;
        float s = g2[o] * rsqrtf(v2[o] + 1e-5f);
        w2p[j] = bf16b((k < 64) ? W2[o * 64 + k] * s : 0.f);
    }
    int l = i - (64 * K1PAD + 128 * K2PAD);
    if (l >= 0 && l < 64) {
        float s = g1[l] * rsqrtf(v1[l] + 1e-5f);
        c1[l] = s * (b1[l] - m1[l]) + be1[l];
    }
    int p = l - 64;
    if (p >= 0 && p < 128) {
        float s = g2[p] * rsqrtf(v2[p] + 1e-5f);
        c2[p] = s * (b2[p] - m2[p]) + be2[p];
    }
}

// ---------------- K1: transpose feat -> fxt[b][n][68], pts4, out0, out2 ----
__global__ __launch_bounds__(512) void k1_prep(const float* __restrict__ xyz,
                                               const float* __restrict__ feat,
                                               float* __restrict__ fxt,
                                               float4* __restrict__ pts4,
                                               float* __restrict__ out0,
                                               float* __restrict__ out2) {
    __shared__ float tile[68][65];
    int b  = blockIdx.x >> 7;
    int n0 = (blockIdx.x & 127) * 64;
    int tx = threadIdx.x & 63, ty = threadIdx.x >> 6;
    for (int c = ty; c < 68; c += 8) {
        float v;
        if (c < 64)       v = feat[((size_t)b * 64 + c) * NN + n0 + tx];
        else if (c < 67)  v = xyz[((size_t)b * NN + n0 + tx) * 3 + (c - 64)];
        else              v = 0.f;
        tile[c][tx] = v;
    }
    __syncthreads();
    size_t base = ((size_t)b * NN + n0) * 68;
    for (int e = threadIdx.x; e < 64 * 68; e += 512) {
        int nl = e / 68, c = e - nl * 68;
        fxt[base + e] = tile[c][nl];
    }
    if (threadIdx.x < 64) {
        int n = n0 + threadIdx.x;
        float x = tile[64][threadIdx.x], y = tile[65][threadIdx.x], z = tile[66][threadIdx.x];
        pts4[(size_t)b * NN + n] = make_float4(x, y, z, x * x + y * y + z * z);
        if (n0 < PP) out2[b * PP + n] = (float)n;
    }
    if (n0 < PP) {
        for (int e = threadIdx.x; e < 64 * 3; e += 512) {
            int nl = e / 3, d = e - nl * 3;
            out0[((size_t)b * PP + n0 + nl) * 3 + d] = tile[64 + d][nl];
        }
    }
}

// ---------------- K2 v5: exact KNN; tails via broadcast-LDS rank-select ----
// 256 blocks x 1024 thr, whole batch staged once (128 KB), one barrier.
// Tail per query: threshold T (4-interleaved value bitonic), rescan+ballot
// compaction into per-wave scratch, then RANK-SELECT: each lane owns survivor
// `lane`, loops j<M reading scratch[j] (same-address broadcast, conflict-free)
// accumulating rank by (d,idx) lex compare -> no 21-stage ds_bpermute chains.
__global__ __launch_bounds__(1024, 2) void k2_knn(const float4* __restrict__ pts4,
                                                  int* __restrict__ knn) {
    __shared__ float4 stage[8192];           // 128 KB
    __shared__ float2 scratch[16][2][64];    // 16 KB dual per-wave buffers
    int lane = threadIdx.x & 63;
    int wv   = threadIdx.x >> 6;
    int b    = blockIdx.x >> 5;
    int q0   = (blockIdx.x & 31) * 64 + wv * 4;
    size_t pb = (size_t)b * NN;

    float4 qc = make_float4(0.f, 0.f, 0.f, 0.f);
    if (lane < 4) qc = pts4[pb + q0 + lane];
    float qx2 = -2.f * qc.x, qy2 = -2.f * qc.y, qz2 = -2.f * qc.z;
    float bx[4], by[4], bz[4];
#pragma unroll
    for (int q = 0; q < 4; ++q) {
        bx[q] = __shfl(qx2, q); by[q] = __shfl(qy2, q); bz[q] = __shfl(qz2, q);
    }

    // stage all 8192 points, swizzled slot(r,c) = r*64 + ((c + (r>>1)) & 63)
#pragma unroll
    for (int i = 0; i < 8; ++i) {
        int p = i * 1024 + threadIdx.x;
        float4 v = pts4[pb + p];
        int r = p >> 6, c = p & 63;
        stage[(r << 6) | ((c + (r >> 1)) & 63)] = v;
    }
    __syncthreads();   // the only block barrier

    // Phase 1: per-lane min over its 128 candidates (rows 2L, 2L+1)
    float m[4];
#pragma unroll
    for (int q = 0; q < 4; ++q) m[q] = FLTMAX;
#pragma unroll
    for (int rr = 0; rr < 2; ++rr) {
        int rowbase = (2 * lane + rr) << 6;
#pragma unroll
        for (int j8 = 0; j8 < 8; ++j8) {
            float4 cc[8];
#pragma unroll
            for (int i = 0; i < 8; ++i)
                cc[i] = stage[rowbase | ((j8 * 8 + i + lane) & 63)];
#pragma unroll
            for (int q = 0; q < 4; ++q) {
                float x = bx[q], y = by[q], z = bz[q];
#pragma unroll
                for (int i = 0; i < 8; i += 2) {
                    float e0 = fmaf(z, cc[i].z, fmaf(y, cc[i].y, fmaf(x, cc[i].x, cc[i].w)));
                    float e1 = fmaf(z, cc[i+1].z, fmaf(y, cc[i+1].y, fmaf(x, cc[i+1].x, cc[i+1].w)));
                    m[q] = fminf(fminf(m[q], e0), e1);
                }
            }
        }
    }

    // Interleaved threshold sorts: T[q] = 16th smallest of 64 lane-mins
    float sv0 = m[0], sv1 = m[1], sv2 = m[2], sv3 = m[3];
#pragma unroll
    for (int k = 2; k <= 64; k <<= 1) {
#pragma unroll
        for (int j = k >> 1; j > 0; j >>= 1) {
            bool keepMin = (((lane & k) == 0) == ((lane & j) == 0));
            float p0 = __shfl_xor(sv0, j, 64);
            float p1 = __shfl_xor(sv1, j, 64);
            float p2 = __shfl_xor(sv2, j, 64);
            float p3 = __shfl_xor(sv3, j, 64);
            sv0 = keepMin ? fminf(sv0, p0) : fmaxf(sv0, p0);
            sv1 = keepMin ? fminf(sv1, p1) : fmaxf(sv1, p1);
            sv2 = keepMin ? fminf(sv2, p2) : fmaxf(sv2, p2);
            sv3 = keepMin ? fminf(sv3, p3) : fmaxf(sv3, p3);
        }
    }
    float T[4];
    T[0] = __shfl(sv0, 15, 64); T[1] = __shfl(sv1, 15, 64);
    T[2] = __shfl(sv2, 15, 64); T[3] = __shfl(sv3, 15, 64);

    unsigned long long below = (lane == 63) ? 0x7FFFFFFFFFFFFFFFull
                                            : ((1ull << lane) - 1ull);
#pragma unroll
    for (int pr = 0; pr < 4; pr += 2) {
        int Ms[2];
        // rescan + ballot-prefix compaction into dual scratch buffers
#pragma unroll
        for (int u = 0; u < 2; ++u) {
            int q = pr + u;
            float x = bx[q], y = by[q], z = bz[q], tq = T[q];
            unsigned long long rm = __ballot(m[q] <= tq);
            int cnt = 0;
            while (rm) {
                int sl = __ffsll((long long)rm) - 1; rm &= rm - 1;
                int phys = (lane + sl) & 63;
                float4 c0 = stage[((2 * sl) << 6) | phys];
                float4 c1 = stage[((2 * sl + 1) << 6) | phys];
                float e0 = fmaf(z, c0.z, fmaf(y, c0.y, fmaf(x, c0.x, c0.w)));
                float e1 = fmaf(z, c1.z, fmaf(y, c1.y, fmaf(x, c1.x, c1.w)));
                unsigned long long b0 = __ballot(e0 <= tq);
                if (e0 <= tq) {
                    int pos = cnt + __popcll(b0 & below);
                    if (pos < 64)
                        scratch[wv][u][pos] = make_float2(e0, __int_as_float(sl * 128 + lane));
                }
                cnt += __popcll(b0);
                unsigned long long b1 = __ballot(e1 <= tq);
                if (e1 <= tq) {
                    int pos = cnt + __popcll(b1 & below);
                    if (pos < 64)
                        scratch[wv][u][pos] = make_float2(e1, __int_as_float(sl * 128 + 64 + lane));
                }
                cnt += __popcll(b1);
            }
            Ms[u] = min(cnt, 64);
        }
        LDS_FENCE();   // drain compaction writes before readback
        // rank-select both queries (broadcast LDS reads, pipelined VALU)
#pragma unroll
        for (int u = 0; u < 2; ++u) {
            int M = Ms[u];
            float2 own = scratch[wv][u][lane];
            float di = own.x; int ni = __float_as_int(own.y);
            int rank = 0;
            const float2* buf = &scratch[wv][u][0];
#pragma unroll 4
            for (int j = 0; j < M; ++j) {
                float2 e = buf[j];
                int nj = __float_as_int(e.y);
                rank += (e.x < di || (e.x == di && nj < ni)) ? 1 : 0;
            }
            if (lane < M && rank < 16)
                knn[((size_t)(b * PP + q0 + pr + u)) * KK + rank] = ni;
        }
        LDS_FENCE();   // order scratch reuse across pairs
    }
}

// ---------------- K3 v4: no-spill 4-wave blocks, w1 in LDS, h1 overlay ----
__global__ __launch_bounds__(256, 2) void k3_mlp(const float* __restrict__ fxt,
                                                 const int* __restrict__ knn,
                                                 const unsigned short* __restrict__ w1p,
                                                 const unsigned short* __restrict__ w2p,
                                                 const float* __restrict__ c1,
                                                 const float* __restrict__ c2,
                                                 float* __restrict__ out1) {
    __shared__ __align__(16) char smem[4 * 5632];
    __shared__ float otile[16][132];
    __shared__ __align__(16) unsigned short w1lds[64 * 168];   // 21,504 B
    int lane = threadIdx.x & 63;
    int wv   = threadIdx.x >> 6;
    int b    = blockIdx.x & 7;        // XCD-aware batch assignment
    int qg   = blockIdx.x >> 3;
    int qbase = qg * 16;
    char* seg = smem + wv * 5632;
    float4* sh_t4 = (float4*)(seg + 5120);
    unsigned* sh_tbd = (unsigned*)(seg + 5392);
    unsigned short* h1l = (unsigned short*)(seg);              // overlaid on E
    const float4* fx4 = (const float4*)fxt;

    int col = lane & 15, quad = lane >> 4;
    int r = lane >> 2, s = lane & 3;

    // stage w1p (64x160) into LDS rows of stride 168 (bank-balanced fragments)
    {
        const unsigned* src = (const unsigned*)w1p;
        unsigned* dst = (unsigned*)w1lds;
        for (int t = threadIdx.x; t < 5120; t += 256) {
            int row = t / 80, c = t - row * 80;
            dst[row * 84 + c] = src[t];
        }
    }

    s16x8 w2f[2][8];
#pragma unroll
    for (int ks = 0; ks < 2; ++ks)
#pragma unroll
        for (int nt = 0; nt < 8; ++nt)
            w2f[ks][nt] = *(const s16x8*)(w2p + (nt * 16 + col) * K2PAD + ks * 32 + quad * 8);
    float c1v[4], c2v[8];
#pragma unroll
    for (int nt = 0; nt < 4; ++nt) c1v[nt] = c1[nt * 16 + col];
#pragma unroll
    for (int nt = 0; nt < 8; ++nt) c2v[nt] = c2[nt * 16 + col];

    // all 64 knn indices for this wave's 4 queries (contiguous load)
    int idxAll = knn[((size_t)(b * PP + qbase + wv * 4)) * KK + lane];

    __syncthreads();   // w1lds visible to all waves

    float4 cc[2][5];
    float4 tv[2];

#define PREFETCH(buf, qi_) {                                                  \
        int q_ = qbase + wv * 4 + (qi_);                                      \
        tv[buf] = make_float4(0.f, 0.f, 0.f, 0.f);                            \
        if (lane < 17) tv[buf] = fx4[((size_t)b * NN + q_) * 17 + lane];      \
        int nidx_ = __shfl(idxAll, (qi_) * 16 + r, 64);                       \
        const float4* rowp_ = fx4 + ((size_t)b * NN + nidx_) * 17;            \
        cc[buf][0] = rowp_[s];      cc[buf][1] = rowp_[4 + s];                \
        cc[buf][2] = rowp_[8 + s];  cc[buf][3] = rowp_[12 + s];               \
        cc[buf][4] = rowp_[16]; }

    PREFETCH(0, 0);

#pragma unroll
    for (int qi = 0; qi < 4; ++qi) {
        int cur = qi & 1, nxt = cur ^ 1;
        // stage t row
        if (lane < 17) {
            float4 v = tv[cur];
            sh_t4[lane] = v;
            sh_tbd[lane * 2]     = pk2(v.x, v.y);
            sh_tbd[lane * 2 + 1] = pk2(v.z, v.w);
        }
        LDS_FENCE();
        // build E row r from prefetched registers + re-zero E K-pads
        char* erow = seg + r * 320;
#pragma unroll
        for (int j = 0; j < 4; ++j) {
            int c4 = j * 4 + s;
            float4 v = cc[cur][j], t = sh_t4[c4];
            *(unsigned*)(erow + c4 * 8)     = pk2(v.x - t.x, v.y - t.y);
            *(unsigned*)(erow + c4 * 8 + 4) = pk2(v.z - t.z, v.w - t.w);
        }
        if (s == 0) {
            float4 v = cc[cur][4], t = sh_t4[16];
            *(unsigned*)(erow + 128) = pk2(v.x - t.x, v.y - t.y);
            *(unsigned*)(erow + 132) = pk2(v.z - t.z, v.w - t.w);
        }
        for (int j = s; j < 34; j += 4)
            *(unsigned*)(erow + 144 + j * 4) = sh_tbd[j];
#pragma unroll
        for (int i = lane; i < 192; i += 64) {            // E pad dwords
            int rr = i / 12, jj = i - rr * 12;
            int dw = (jj < 2) ? (34 + jj) : (68 + jj);
            *(unsigned*)(seg + rr * 320 + dw * 4) = 0u;
        }
        // kick next query's gather while GEMMs run
        if (qi < 3) PREFETCH(nxt, qi + 1);
        LDS_FENCE();
        // GEMM1: h1 = relu(E * W1^T + c1); B-fragments from w1lds
        f32x4 acc1[4];
#pragma unroll
        for (int nt = 0; nt < 4; ++nt) acc1[nt] = (f32x4){0.f, 0.f, 0.f, 0.f};
#pragma unroll
        for (int ks = 0; ks < 5; ++ks) {
            s16x8 a = *(const s16x8*)(seg + col * 320 + ks * 64 + quad * 16);
#pragma unroll
            for (int nt = 0; nt < 4; ++nt) {
                s16x8 bf = *(const s16x8*)(w1lds + (nt * 16 + col) * 168 + ks * 32 + quad * 8);
                acc1[nt] = __builtin_amdgcn_mfma_f32_16x16x32_bf16(a, bf, acc1[nt], 0, 0, 0);
            }
        }
        // write h1 (overlaid on E; E fully consumed by in-order LDS reads)
#pragma unroll
        for (int nt = 0; nt < 4; ++nt) {
#pragma unroll
            for (int rr = 0; rr < 4; ++rr) {
                float y = fmaxf(acc1[nt][rr] + c1v[nt], 0.f);
                h1l[(quad * 4 + rr) * K2PAD + nt * 16 + col] = bf16b(y);
            }
        }
        {   // re-zero h1 K-pad (cols 64..71): 16 rows x 4 dwords, 1/lane
            int rr = lane >> 2, dd = lane & 3;
            *(unsigned*)(seg + rr * 144 + 128 + dd * 4) = 0u;
        }
        LDS_FENCE();
        // GEMM2 + maxpool over 16 edges
        f32x4 acc2[8];
#pragma unroll
        for (int nt = 0; nt < 8; ++nt) acc2[nt] = (f32x4){0.f, 0.f, 0.f, 0.f};
#pragma unroll
        for (int ks = 0; ks < 2; ++ks) {
            s16x8 a = *(const s16x8*)(seg + col * 144 + ks * 64 + quad * 16);
#pragma unroll
            for (int nt = 0; nt < 8; ++nt)
                acc2[nt] = __builtin_amdgcn_mfma_f32_16x16x32_bf16(a, w2f[ks][nt], acc2[nt], 0, 0, 0);
        }
#pragma unroll
        for (int nt = 0; nt < 8; ++nt) {
            float m0 = fmaxf(fmaxf(acc2[nt][0], acc2[nt][1]), fmaxf(acc2[nt][2], acc2[nt][3]));
            m0 = m0 + c2v[nt];
            m0 = fmaxf(m0, 0.f);
            m0 = fmaxf(m0, __shfl_xor(m0, 16, 64));
            m0 = fmaxf(m0, __shfl_xor(m0, 32, 64));
            if (quad == 0)
                otile[wv * 4 + qi][nt * 16 + col] = m0;
        }
        LDS_FENCE();
    }
    __syncthreads();
    // coalesced store: consecutive threads -> consecutive q, same channel
    for (int i = threadIdx.x; i < H2 * 16; i += 256) {
        int ch = i >> 4, q = i & 15;
        out1[((size_t)(b * H2 + ch)) * PP + qbase + q] = otile[q][ch];
    }
#undef PREFETCH
}

extern "C" void kernel_launch(void* const* d_in, const int* in_sizes, int n_in,
                              void* d_out, int out_size, void* d_ws, size_t ws_size,
                              hipStream_t stream) {
    const float* xyz  = (const float*)d_in[0];
    const float* feat = (const float*)d_in[1];
    const float* W1   = (const float*)d_in[2];
    const float* b1   = (const float*)d_in[3];
    const float* g1   = (const float*)d_in[4];
    const float* be1  = (const float*)d_in[5];
    const float* m1   = (const float*)d_in[6];
    const float* v1   = (const float*)d_in[7];
    const float* W2   = (const float*)d_in[8];
    const float* b2   = (const float*)d_in[9];
    const float* g2   = (const float*)d_in[10];
    const float* be2  = (const float*)d_in[11];
    const float* m2   = (const float*)d_in[12];
    const float* v2   = (const float*)d_in[13];

    char* ws = (char*)d_ws;
    float*          fxt  = (float*)(ws + OFF_FXT);
    float4*         pts4 = (float4*)(ws + OFF_PTS4);
    int*            knn  = (int*)(ws + OFF_KNN);
    unsigned short* w1p  = (unsigned short*)(ws + OFF_W1P);
    unsigned short* w2p  = (unsigned short*)(ws + OFF_W2P);
    float*          c1   = (float*)(ws + OFF_C1);
    float*          c2   = (float*)(ws + OFF_C2);

    float* out0 = (float*)d_out;
    float* out1 = out0 + (size_t)BB * PP * 3;
    float* out2 = out1 + (size_t)BB * H2 * PP;

    hipLaunchKernelGGL(k0_weights, dim3(77), dim3(256), 0, stream,
                       W1, b1, g1, be1, m1, v1, W2, b2, g2, be2, m2, v2,
                       w1p, w2p, c1, c2);
    hipLaunchKernelGGL(k1_prep, dim3(1024), dim3(512), 0, stream,
                       xyz, feat, fxt, pts4, out0, out2);
    hipLaunchKernelGGL(k2_knn, dim3(256), dim3(1024), 0, stream, pts4, knn);
    hipLaunchKernelGGL(k3_mlp, dim3(1024), dim3(256), 0, stream,
                       fxt, knn, w1p, w2p, c1, c2, out1);
}